// Round 11
// baseline (54.340 us; speedup 1.0000x reference)
//
#include <hip/hip_runtime.h>
#include <cstdint>
#include <cstddef>

#define LSEQ   2048
#define CHN    512
#define NH     8
#define HD     64
#define NTAP   33
#define NPOS   4096
#define MAXREC 256.0f

typedef __bf16   bf16x8 __attribute__((ext_vector_type(8)));
typedef __bf16   bf16x4 __attribute__((ext_vector_type(4)));
typedef float    f32x4  __attribute__((ext_vector_type(4)));
typedef _Float16 f16x2  __attribute__((ext_vector_type(2)));

__device__ __forceinline__ float silu_f(float v) {
    return v / (1.0f + expf(-v));
}

__device__ __forceinline__ void gload_lds16(const void* g, void* l) {
    __builtin_amdgcn_global_load_lds((const __attribute__((address_space(1))) void*)g,
                                     (__attribute__((address_space(3))) void*)l, 16, 0, 0);
}

__device__ __forceinline__ float fdot2f(unsigned a, unsigned b, float c) {
#if __has_builtin(__builtin_amdgcn_fdot2)
    return __builtin_amdgcn_fdot2(__builtin_bit_cast(f16x2, a),
                                  __builtin_bit_cast(f16x2, b), c, false);
#else
    f16x2 av = __builtin_bit_cast(f16x2, a);
    f16x2 bv = __builtin_bit_cast(f16x2, b);
    return c + (float)av[0] * (float)bv[0] + (float)av[1] * (float)bv[1];
#endif
}

// ---------------------------------------------------------------------------
// Tiled-bf16 layout (64 rows x 64 k per tile), k permuted per 32-block:
//   col' = 32*(k/32) + (k%4) + 4*((k/16)&1) + 8*((k%16)/4)
// XOR bank swizzle on byte addr within row: byte ^= (row&7)<<4.
// One MFMA 16x16x32 fragment == one contiguous 16B ds_read_b128.
// ---------------------------------------------------------------------------

// ---------------------------------------------------------------------------
// Fused prep kernel. Grid 1280 blocks x 256 threads (proven structure):
//   blocks [0,256):   convert kernel_w / out_w -> tiled bf16
//   blocks [256,1280): 4 positions/block: stage wave_w in LDS, x row ->
//       tiled bf16 xb, x pair rows -> xpair f16x2, matvec -> fph[pos][16]
//       (freq in [0..8), phase in [8..16)) — NO tap table anymore.
// ---------------------------------------------------------------------------
__global__ __launch_bounds__(256) void fused_prep(
    const float* __restrict__ x, const float* __restrict__ ww,
    const float* __restrict__ wb,
    const float* __restrict__ kernel_w, __bf16* __restrict__ kwb,
    const float* __restrict__ out_w,    __bf16* __restrict__ owb,
    float* __restrict__ fph, __bf16* __restrict__ xb,
    unsigned* __restrict__ xpair)
{
    __shared__ float wwS[16 * 512];
    __shared__ float fphS[4][16];

    int tid = threadIdx.x;
    if (blockIdx.x < 256) {
        // ---- weight conversion ----
        const float* src = (blockIdx.x < 128) ? kernel_w : out_w;
        __bf16*      dst = (blockIdx.x < 128) ? kwb : owb;
        int C = ((blockIdx.x & 127) * 256 + tid);
        int tileIdx = C / (64 * 8);
        int o    = (C % (64 * 8)) * 16;
        int rowL = o >> 7;
        int cb   = o & 127;
        int cbu  = cb ^ ((rowL & 7) << 4);
        int block = cbu >> 6;
        int g2    = (cbu >> 4) & 3;
        int rs = (tileIdx >> 3) * 64 + rowL;
        int kb = (tileIdx & 7) * 64 + block * 32 + g2 * 4;
        const float* s = src + (size_t)rs * 512 + kb;
        float4 v0 = *(const float4*)s;
        float4 v1 = *(const float4*)(s + 16);
        bf16x8 r;
        r[0] = (__bf16)v0.x; r[1] = (__bf16)v0.y; r[2] = (__bf16)v0.z; r[3] = (__bf16)v0.w;
        r[4] = (__bf16)v1.x; r[5] = (__bf16)v1.y; r[6] = (__bf16)v1.z; r[7] = (__bf16)v1.w;
        *(bf16x8*)(dst + (size_t)C * 8) = r;
        return;
    }

    // ---- wave path ----
    #pragma unroll
    for (int j = 0; j < 8; ++j) {
        int idx = tid * 4 + j * 1024;
        *(float4*)&wwS[idx] = *(const float4*)&ww[idx];
    }

    int wid  = tid >> 6;
    int lane = tid & 63;
    int pos  = (blockIdx.x - 256) * 4 + wid;
    int t    = pos & (LSEQ - 1);

    const float* xrow = x + (size_t)pos * CHN;
    float4 xa = *(const float4*)(xrow + lane * 8);
    float4 xv = *(const float4*)(xrow + lane * 8 + 4);
    int nxt = (t == LSEQ - 1) ? pos : pos + 1;
    const float* nrow = x + (size_t)nxt * CHN;
    float4 na = *(const float4*)(nrow + lane * 8);
    float4 nv = *(const float4*)(nrow + lane * 8 + 4);
    float xs[8];
    #pragma unroll
    for (int j = 0; j < 8; ++j) xs[j] = xrow[lane + 64 * j];

    // tiled-bf16 store of this x row
    {
        int kloc = (lane * 8) & 63;
        int kt   = lane >> 3;
        int rowL = pos & 63;
        int blk  = kloc >> 5;
        int kkA  = kloc & 31;
        int kkV  = kkA + 4;
        int colA = blk * 32 + 8 * ((kkA & 15) >> 2) + 4 * ((kkA >> 4) & 1);
        int colV = blk * 32 + 8 * ((kkV & 15) >> 2) + 4 * ((kkV >> 4) & 1);
        int sw   = (rowL & 7) << 4;
        char* base = (char*)xb + (((size_t)(pos >> 6) * 8 + kt) * 8192) + rowL * 128;
        bf16x4 va = { (__bf16)xa.x, (__bf16)xa.y, (__bf16)xa.z, (__bf16)xa.w };
        bf16x4 vv = { (__bf16)xv.x, (__bf16)xv.y, (__bf16)xv.z, (__bf16)xv.w };
        *(bf16x4*)(base + ((colA * 2) ^ sw)) = va;
        *(bf16x4*)(base + ((colV * 2) ^ sw)) = vv;
    }

    // xpair store: (f16 x[pos][d], f16 x[pos+1][d]) packed u32
    {
        float va8[8] = {xa.x, xa.y, xa.z, xa.w, xv.x, xv.y, xv.z, xv.w};
        float nb8[8] = {na.x, na.y, na.z, na.w, nv.x, nv.y, nv.z, nv.w};
        unsigned u[8];
        #pragma unroll
        for (int j = 0; j < 8; ++j) {
            unsigned short lo = __builtin_bit_cast(unsigned short, (_Float16)va8[j]);
            unsigned short hi = __builtin_bit_cast(unsigned short, (_Float16)nb8[j]);
            u[j] = (unsigned)lo | ((unsigned)hi << 16);
        }
        unsigned* dp = xpair + (size_t)pos * 512 + lane * 8;
        *(uint4*)dp       = make_uint4(u[0], u[1], u[2], u[3]);
        *(uint4*)(dp + 4) = make_uint4(u[4], u[5], u[6], u[7]);
    }

    __syncthreads();   // wwS ready (only barrier needed)

    #pragma unroll
    for (int o = 0; o < 16; ++o) {
        const float* wr = &wwS[o * 512 + lane];
        float p = 0.0f;
        #pragma unroll
        for (int j = 0; j < 8; ++j) p = fmaf(xs[j], wr[64 * j], p);
        #pragma unroll
        for (int off = 32; off > 0; off >>= 1) p += __shfl_xor(p, off);
        if (lane == 0) {
            float v = p + wb[o];
            float s = silu_f(v);
            fphS[wid][o] = (o < 8) ? (1.0f + 15.0f / (1.0f + expf(-s)))
                                   : (tanhf(s) * 16.0f);
        }
    }
    // fphS[wid] written and read by the SAME wave: per-wave DS ordering
    // (compiler-inserted lgkmcnt) suffices — no block barrier.
    if (lane < 16) fph[(size_t)pos * 16 + lane] = fphS[wid][lane];
}

// ---------------------------------------------------------------------------
// bf16 MFMA GEMM, BM=BN=64, BK=64, 4 waves (2x2), double-buffered (proven).
// COMPACT: h == bn (BN=64); for taps sc=(n&63)<33, compute (i0,w) directly
//          from fph[pos][16] (p = t+ph+(sc-16)*f, clamped; i0=floor) and
//          write qtab[pos][h][sc] = { pack_f16(k*(1-w), k*w), i0*2048 }.
//          i0=2047/w=0 is safe: xpair row 2047's hi-half duplicates row 2047.
// else:    write full f32 silu'd [M,512].
// ---------------------------------------------------------------------------
template<bool COMPACT>
__global__ __launch_bounds__(256) void gemm_mfma64(
    const __bf16* __restrict__ At, const __bf16* __restrict__ Bt,
    const float* __restrict__ bias, float* __restrict__ C,
    uint2* __restrict__ qtab, const float* __restrict__ fph)
{
    __shared__ __bf16 As[2][64 * 64];
    __shared__ __bf16 Bs[2][64 * 64];

    int bm = blockIdx.x, bn = blockIdx.y;
    int tid  = threadIdx.x;
    int lane = tid & 63;
    int wid  = tid >> 6;
    int wr = wid >> 1, wc = wid & 1;
    int lg = lane >> 4, l15 = lane & 15;

    const __bf16* Abase = At + (size_t)bm * 8 * 4096;
    const __bf16* Bbase = Bt + (size_t)bn * 8 * 4096;

    int offA[2][2], offB[2][2];
    #pragma unroll
    for (int mi = 0; mi < 2; ++mi) {
        int row = wr * 32 + mi * 16 + l15;
        #pragma unroll
        for (int ks = 0; ks < 2; ++ks)
            offA[mi][ks] = row * 128 + (((ks << 6) | (lg << 4)) ^ ((row & 7) << 4));
    }
    #pragma unroll
    for (int ni = 0; ni < 2; ++ni) {
        int n = wc * 32 + ni * 16 + l15;
        #pragma unroll
        for (int ks = 0; ks < 2; ++ks)
            offB[ni][ks] = n * 128 + (((ks << 6) | (lg << 4)) ^ ((n & 7) << 4));
    }

    f32x4 acc[2][2] = {};

    auto stage = [&](int b, int kt) {
        const __bf16* ga = Abase + (size_t)kt * 4096 + tid * 8;
        const __bf16* gb = Bbase + (size_t)kt * 4096 + tid * 8;
        __bf16* la = &As[b][tid * 8];
        __bf16* lb = &Bs[b][tid * 8];
        #pragma unroll
        for (int c = 0; c < 2; ++c) gload_lds16(ga + c * 2048, la + c * 2048);
        #pragma unroll
        for (int c = 0; c < 2; ++c) gload_lds16(gb + c * 2048, lb + c * 2048);
    };

    stage(0, 0);
    #pragma unroll
    for (int kt = 0; kt < 8; ++kt) {
        int cur = kt & 1;
        if (kt < 7) stage(cur ^ 1, kt + 1);
        __builtin_amdgcn_sched_barrier(0);
        if (kt < 7) asm volatile("s_waitcnt vmcnt(4)" ::: "memory");
        else        asm volatile("s_waitcnt vmcnt(0)" ::: "memory");
        __builtin_amdgcn_s_barrier();
        const char* ab = (const char*)&As[cur][0];
        const char* bb = (const char*)&Bs[cur][0];
        #pragma unroll
        for (int ks = 0; ks < 2; ++ks) {
            bf16x8 af[2], bfr[2];
            #pragma unroll
            for (int mi = 0; mi < 2; ++mi) af[mi]  = *(const bf16x8*)(ab + offA[mi][ks]);
            #pragma unroll
            for (int ni = 0; ni < 2; ++ni) bfr[ni] = *(const bf16x8*)(bb + offB[ni][ks]);
            #pragma unroll
            for (int mi = 0; mi < 2; ++mi)
                #pragma unroll
                for (int ni = 0; ni < 2; ++ni)
                    acc[mi][ni] = __builtin_amdgcn_mfma_f32_16x16x32_bf16(
                        af[mi], bfr[ni], acc[mi][ni], 0, 0, 0);
        }
        __builtin_amdgcn_s_barrier();
    }

    // C/D frag: col = l&15, row = (l>>4)*4 + j
    int n0 = bn * 64 + wc * 32 + l15;
    float bv0 = bias ? bias[n0] : 0.0f;
    float bv1 = bias ? bias[n0 + 16] : 0.0f;

    if (COMPACT) {
        // h == bn; sc = wc*32 + l15 + ni*16
        #pragma unroll
        for (int mi = 0; mi < 2; ++mi) {
            #pragma unroll
            for (int j = 0; j < 4; ++j) {
                int m_ = bm * 64 + wr * 32 + mi * 16 + lg * 4 + j;  // global pos
                int t  = m_ & (LSEQ - 1);
                float tf = (float)t;
                float f  = fph[(size_t)m_ * 16 + bn];
                float ph = fph[(size_t)m_ * 16 + 8 + bn];
                float base = tf + ph;
                float lo = fmaxf(tf - MAXREC, 0.0f);
                float hi = fminf(tf + MAXREC, (float)(LSEQ - 1));
                #pragma unroll
                for (int ni = 0; ni < 2; ++ni) {
                    int sc = wc * 32 + l15 + ni * 16;
                    if (sc < NTAP) {
                        float v = silu_f(acc[mi][ni][j] + (ni ? bv1 : bv0));
                        float p = fmaf((float)(sc - 16), f, base);
                        p = fminf(fmaxf(p, lo), hi);
                        float p0 = floorf(p);
                        float w  = p - p0;
                        int i0 = (int)p0;
                        float t1 = v * w;
                        unsigned short c0 =
                            __builtin_bit_cast(unsigned short, (_Float16)(v - t1));
                        unsigned short c1 =
                            __builtin_bit_cast(unsigned short, (_Float16)t1);
                        uint2 qv;
                        qv.x = (unsigned)c0 | ((unsigned)c1 << 16);
                        qv.y = (unsigned)i0 << 11;       // byte offset i0*2048
                        qtab[(size_t)m_ * (NH * NTAP) + bn * NTAP + sc] = qv;
                    }
                }
            }
        }
    } else {
        #pragma unroll
        for (int ni = 0; ni < 2; ++ni) {
            int n = n0 + ni * 16;
            #pragma unroll
            for (int mi = 0; mi < 2; ++mi) {
                int m = bm * 64 + wr * 32 + mi * 16 + lg * 4;
                #pragma unroll
                for (int j = 0; j < 4; ++j)
                    C[(size_t)(m + j) * 512 + n] = silu_f(acc[mi][ni][j]);
            }
        }
    }
}

// ---------------------------------------------------------------------------
// Gather conv (proven R10 structure). One wave per (t,h); lane = dim d;
// batch = blockIdx.y. Stage the wave's 33 contiguous qtab entries into LDS;
// per 11-tap chunk keep 11 gathers in flight, accumulate via v_dot2_f32_f16.
// XCD-aware block swizzle. Writes hidden as bf16 in the tiled GEMM layout.
// ---------------------------------------------------------------------------
__global__ __launch_bounds__(256, 4) void gather_conv(
    const unsigned* __restrict__ xpair, const uint2* __restrict__ qtab,
    __bf16* __restrict__ hb)
{
    __shared__ uint2 qs[4][NTAP + 3];

    int wid  = threadIdx.x >> 6;
    int lane = threadIdx.x & 63;
    int bid  = blockIdx.x;                       // 4096 = 8 XCDs * 512
    int nb   = ((bid & 7) << 9) | (bid >> 3);    // bijective XCD-chunked swizzle
    int wix  = nb * 4 + wid;                     // t*8 + h
    int h = wix & 7, t = wix >> 3;
    int b = blockIdx.y;

    int pos = b * LSEQ + t;
    const char* xpb = (const char*)xpair + (size_t)b * (LSEQ * 2048);
    int xoff = (h * HD + lane) * 4;
    const uint2* qp = qtab + (size_t)pos * (NH * NTAP) + h * NTAP;

    if (lane < NTAP) qs[wid][lane] = qp[lane];
    __syncthreads();

    float acc = 0.0f;
    #pragma unroll
    for (int c = 0; c < 3; ++c) {
        unsigned cx[11];
        unsigned gv[11];
        #pragma unroll
        for (int i = 0; i < 11; ++i) {
            uint2 q = qs[wid][c * 11 + i];
            cx[i] = q.x;
            unsigned off = __builtin_amdgcn_readfirstlane(q.y);
            gv[i] = *(const unsigned*)(xpb + off + xoff);
        }
        #pragma unroll
        for (int i = 0; i < 11; ++i) acc = fdot2f(cx[i], gv[i], acc);
    }

    // tiled+permuted+swizzled bf16 write; k-index = h*64 + lane, kt = h
    int tile = (pos >> 6) * 8 + h;
    int rowL = pos & 63;
    int d = lane, blk = d >> 5, kk = d & 31;
    int colp = blk * 32 + (kk & 3) + (((kk >> 4) & 1) << 2) + (((kk & 15) >> 2) << 3);
    int byteS = (colp * 2) ^ ((rowL & 7) << 4);
    hb[(size_t)tile * 4096 + rowL * 64 + (byteS >> 1)] = (__bf16)acc;
}

// ---------------------------------------------------------------------------
extern "C" void kernel_launch(void* const* d_in, const int* in_sizes, int n_in,
                              void* d_out, int out_size, void* d_ws, size_t ws_size,
                              hipStream_t stream)
{
    const float* x        = (const float*)d_in[0];
    const float* wave_w   = (const float*)d_in[1];
    const float* wave_b   = (const float*)d_in[2];
    const float* kernel_w = (const float*)d_in[3];
    const float* kernel_b = (const float*)d_in[4];
    const float* out_w    = (const float*)d_in[5];
    float* out = (float*)d_out;

    char* ws = (char*)d_ws;
    float*    fph   = (float*)ws;     ws += (size_t)NPOS * 16 * 4;          // 256 KB
    uint2*    qtab  = (uint2*)ws;     ws += (size_t)NPOS * NH * NTAP * 8;   // 8.65 MB
    unsigned* xpair = (unsigned*)ws;  ws += (size_t)NPOS * CHN * 4;         // 8 MB
    __bf16*   xb    = (__bf16*)ws;    ws += (size_t)NPOS * CHN * 2;         // 4 MB
    __bf16*   kwb   = (__bf16*)ws;    ws += (size_t)CHN * CHN * 2;          // 0.5 MB
    __bf16*   owb   = (__bf16*)ws;    ws += (size_t)CHN * CHN * 2;          // 0.5 MB
    __bf16*   hidb  = xb;  // xb dead after GEMM1

    fused_prep<<<256 + NPOS / 4, 256, 0, stream>>>(
        x, wave_w, wave_b, kernel_w, kwb, out_w, owb, fph, xb, xpair);

    dim3 gg(NPOS / 64, CHN / 64);
    gemm_mfma64<true><<<gg, 256, 0, stream>>>(xb, kwb, kernel_b, nullptr, qtab, fph);

    gather_conv<<<dim3(LSEQ * NH / 4, 2), 256, 0, stream>>>(xpair, qtab, hidb);

    gemm_mfma64<false><<<gg, 256, 0, stream>>>(hidb, owb, nullptr, out, nullptr, nullptr);
}

// Round 12
// 54.330 us; speedup vs baseline: 1.0002x; 1.0002x over previous
//
#include <hip/hip_runtime.h>
#include <cstdint>
#include <cstddef>

#define LSEQ   2048
#define CHN    512
#define NH     8
#define HD     64
#define NTAP   33
#define NPOS   4096
#define MAXREC 256.0f

typedef __bf16   bf16x8 __attribute__((ext_vector_type(8)));
typedef __bf16   bf16x4 __attribute__((ext_vector_type(4)));
typedef float    f32x4  __attribute__((ext_vector_type(4)));
typedef _Float16 f16x2  __attribute__((ext_vector_type(2)));

__device__ __forceinline__ float silu_f(float v) {
    return v / (1.0f + expf(-v));
}

__device__ __forceinline__ void gload_lds16(const void* g, void* l) {
    __builtin_amdgcn_global_load_lds((const __attribute__((address_space(1))) void*)g,
                                     (__attribute__((address_space(3))) void*)l, 16, 0, 0);
}

__device__ __forceinline__ float fdot2f(unsigned a, unsigned b, float c) {
#if __has_builtin(__builtin_amdgcn_fdot2)
    return __builtin_amdgcn_fdot2(__builtin_bit_cast(f16x2, a),
                                  __builtin_bit_cast(f16x2, b), c, false);
#else
    f16x2 av = __builtin_bit_cast(f16x2, a);
    f16x2 bv = __builtin_bit_cast(f16x2, b);
    return c + (float)av[0] * (float)bv[0] + (float)av[1] * (float)bv[1];
#endif
}

// ---------------------------------------------------------------------------
// Tiled-bf16 layout (64 rows x 64 k per tile), k permuted per 32-block:
//   col' = 32*(k/32) + (k%4) + 4*((k/16)&1) + 8*((k%16)/4)
// XOR bank swizzle on byte addr within row: byte ^= (row&7)<<4.
// One MFMA 16x16x32 fragment == one contiguous 16B ds_read_b128.
// ---------------------------------------------------------------------------

// ---------------------------------------------------------------------------
// Fused prep kernel. Grid 1280 blocks x 256 threads (proven R10 structure):
//   blocks [0,256):   convert kernel_w / out_w -> tiled bf16
//   blocks [256,1280): 4 positions/block: stage wave_w in LDS, x row ->
//       tiled bf16 xb, x pair rows -> xpair f16x2, matvec -> tap table.
//   Only ONE block barrier (wwS staging); fphS is wave-private.
// ---------------------------------------------------------------------------
__global__ __launch_bounds__(256) void fused_prep(
    const float* __restrict__ x, const float* __restrict__ ww,
    const float* __restrict__ wb,
    const float* __restrict__ kernel_w, __bf16* __restrict__ kwb,
    const float* __restrict__ out_w,    __bf16* __restrict__ owb,
    unsigned* __restrict__ tab, __bf16* __restrict__ xb,
    unsigned* __restrict__ xpair)
{
    __shared__ float wwS[16 * 512];
    __shared__ float fphS[4][16];

    int tid = threadIdx.x;
    if (blockIdx.x < 256) {
        // ---- weight conversion ----
        const float* src = (blockIdx.x < 128) ? kernel_w : out_w;
        __bf16*      dst = (blockIdx.x < 128) ? kwb : owb;
        int C = ((blockIdx.x & 127) * 256 + tid);
        int tileIdx = C / (64 * 8);
        int o    = (C % (64 * 8)) * 16;
        int rowL = o >> 7;
        int cb   = o & 127;
        int cbu  = cb ^ ((rowL & 7) << 4);
        int block = cbu >> 6;
        int g2    = (cbu >> 4) & 3;
        int rs = (tileIdx >> 3) * 64 + rowL;
        int kb = (tileIdx & 7) * 64 + block * 32 + g2 * 4;
        const float* s = src + (size_t)rs * 512 + kb;
        float4 v0 = *(const float4*)s;
        float4 v1 = *(const float4*)(s + 16);
        bf16x8 r;
        r[0] = (__bf16)v0.x; r[1] = (__bf16)v0.y; r[2] = (__bf16)v0.z; r[3] = (__bf16)v0.w;
        r[4] = (__bf16)v1.x; r[5] = (__bf16)v1.y; r[6] = (__bf16)v1.z; r[7] = (__bf16)v1.w;
        *(bf16x8*)(dst + (size_t)C * 8) = r;
        return;
    }

    // ---- wave path ----
    #pragma unroll
    for (int j = 0; j < 8; ++j) {
        int idx = tid * 4 + j * 1024;
        *(float4*)&wwS[idx] = *(const float4*)&ww[idx];
    }

    int wid  = tid >> 6;
    int lane = tid & 63;
    int pos  = (blockIdx.x - 256) * 4 + wid;
    int t    = pos & (LSEQ - 1);

    const float* xrow = x + (size_t)pos * CHN;
    float4 xa = *(const float4*)(xrow + lane * 8);
    float4 xv = *(const float4*)(xrow + lane * 8 + 4);
    int nxt = (t == LSEQ - 1) ? pos : pos + 1;
    const float* nrow = x + (size_t)nxt * CHN;
    float4 na = *(const float4*)(nrow + lane * 8);
    float4 nv = *(const float4*)(nrow + lane * 8 + 4);
    float xs[8];
    #pragma unroll
    for (int j = 0; j < 8; ++j) xs[j] = xrow[lane + 64 * j];

    // tiled-bf16 store of this x row
    {
        int kloc = (lane * 8) & 63;
        int kt   = lane >> 3;
        int rowL = pos & 63;
        int blk  = kloc >> 5;
        int kkA  = kloc & 31;
        int kkV  = kkA + 4;
        int colA = blk * 32 + 8 * ((kkA & 15) >> 2) + 4 * ((kkA >> 4) & 1);
        int colV = blk * 32 + 8 * ((kkV & 15) >> 2) + 4 * ((kkV >> 4) & 1);
        int sw   = (rowL & 7) << 4;
        char* base = (char*)xb + (((size_t)(pos >> 6) * 8 + kt) * 8192) + rowL * 128;
        bf16x4 va = { (__bf16)xa.x, (__bf16)xa.y, (__bf16)xa.z, (__bf16)xa.w };
        bf16x4 vv = { (__bf16)xv.x, (__bf16)xv.y, (__bf16)xv.z, (__bf16)xv.w };
        *(bf16x4*)(base + ((colA * 2) ^ sw)) = va;
        *(bf16x4*)(base + ((colV * 2) ^ sw)) = vv;
    }

    // xpair store: (f16 x[pos][d], f16 x[pos+1][d]) packed u32
    {
        float va8[8] = {xa.x, xa.y, xa.z, xa.w, xv.x, xv.y, xv.z, xv.w};
        float nb8[8] = {na.x, na.y, na.z, na.w, nv.x, nv.y, nv.z, nv.w};
        unsigned u[8];
        #pragma unroll
        for (int j = 0; j < 8; ++j) {
            unsigned short lo = __builtin_bit_cast(unsigned short, (_Float16)va8[j]);
            unsigned short hi = __builtin_bit_cast(unsigned short, (_Float16)nb8[j]);
            u[j] = (unsigned)lo | ((unsigned)hi << 16);
        }
        unsigned* dp = xpair + (size_t)pos * 512 + lane * 8;
        *(uint4*)dp       = make_uint4(u[0], u[1], u[2], u[3]);
        *(uint4*)(dp + 4) = make_uint4(u[4], u[5], u[6], u[7]);
    }

    __syncthreads();   // wwS ready (the only block barrier)

    #pragma unroll
    for (int o = 0; o < 16; ++o) {
        const float* wr = &wwS[o * 512 + lane];
        float p = 0.0f;
        #pragma unroll
        for (int j = 0; j < 8; ++j) p = fmaf(xs[j], wr[64 * j], p);
        #pragma unroll
        for (int off = 32; off > 0; off >>= 1) p += __shfl_xor(p, off);
        if (lane == 0) {
            float v = p + wb[o];
            float s = silu_f(v);
            fphS[wid][o] = (o < 8) ? (1.0f + 15.0f / (1.0f + expf(-s)))
                                   : (tanhf(s) * 16.0f);
        }
    }
    // fphS[wid] is written and read by the SAME wave: per-wave DS ordering
    // (compiler-inserted lgkmcnt) suffices — no block barrier. [validated R11]

    // tap table: tab[pos*264 + s*8 + h] = (i0<<16) | f16bits(w)
    float tf = (float)t;
    float lo = fmaxf(tf - MAXREC, 0.0f);
    float hi = fminf(tf + MAXREC, (float)(LSEQ - 1));
    for (int it = lane; it < NH * NTAP; it += 64) {
        int h = it & 7, s = it >> 3;
        float f  = fphS[wid][h];
        float ph = fphS[wid][8 + h];
        float p = (tf + ph) + (float)(s - 16) * f;
        p = fminf(fmaxf(p, lo), hi);
        float p0 = floorf(p);
        float w  = p - p0;
        int i0 = (int)p0;
        if (i0 >= LSEQ - 1) { i0 = LSEQ - 2; w = 1.0f; }
        _Float16 hw = (_Float16)w;
        unsigned u = ((unsigned)i0 << 16) |
                     (unsigned)__builtin_bit_cast(unsigned short, hw);
        tab[(size_t)pos * (NH * NTAP) + it] = u;
    }
}

// ---------------------------------------------------------------------------
// bf16 MFMA GEMM, BM=BN=64, BK=64, 4 waves (2x2), double-buffered (R10).
// COMPACT: for taps (n&63)<33, combine k=silu(acc+bias) with tab's (i0,w)
//          into qtab[pos][h][s] = { pack_f16(k*(1-w), k*w), i0*2048 }.
// else:    write full f32 silu'd [M,512].
// ---------------------------------------------------------------------------
template<bool COMPACT>
__global__ __launch_bounds__(256) void gemm_mfma64(
    const __bf16* __restrict__ At, const __bf16* __restrict__ Bt,
    const float* __restrict__ bias, float* __restrict__ C,
    uint2* __restrict__ qtab, const unsigned* __restrict__ tab)
{
    __shared__ __bf16 As[2][64 * 64];
    __shared__ __bf16 Bs[2][64 * 64];

    int bm = blockIdx.x, bn = blockIdx.y;
    int tid  = threadIdx.x;
    int lane = tid & 63;
    int wid  = tid >> 6;
    int wr = wid >> 1, wc = wid & 1;
    int lg = lane >> 4, l15 = lane & 15;

    const __bf16* Abase = At + (size_t)bm * 8 * 4096;
    const __bf16* Bbase = Bt + (size_t)bn * 8 * 4096;

    int offA[2][2], offB[2][2];
    #pragma unroll
    for (int mi = 0; mi < 2; ++mi) {
        int row = wr * 32 + mi * 16 + l15;
        #pragma unroll
        for (int ks = 0; ks < 2; ++ks)
            offA[mi][ks] = row * 128 + (((ks << 6) | (lg << 4)) ^ ((row & 7) << 4));
    }
    #pragma unroll
    for (int ni = 0; ni < 2; ++ni) {
        int n = wc * 32 + ni * 16 + l15;
        #pragma unroll
        for (int ks = 0; ks < 2; ++ks)
            offB[ni][ks] = n * 128 + (((ks << 6) | (lg << 4)) ^ ((n & 7) << 4));
    }

    f32x4 acc[2][2] = {};

    auto stage = [&](int b, int kt) {
        const __bf16* ga = Abase + (size_t)kt * 4096 + tid * 8;
        const __bf16* gb = Bbase + (size_t)kt * 4096 + tid * 8;
        __bf16* la = &As[b][tid * 8];
        __bf16* lb = &Bs[b][tid * 8];
        #pragma unroll
        for (int c = 0; c < 2; ++c) gload_lds16(ga + c * 2048, la + c * 2048);
        #pragma unroll
        for (int c = 0; c < 2; ++c) gload_lds16(gb + c * 2048, lb + c * 2048);
    };

    stage(0, 0);
    #pragma unroll
    for (int kt = 0; kt < 8; ++kt) {
        int cur = kt & 1;
        if (kt < 7) stage(cur ^ 1, kt + 1);
        __builtin_amdgcn_sched_barrier(0);
        if (kt < 7) asm volatile("s_waitcnt vmcnt(4)" ::: "memory");
        else        asm volatile("s_waitcnt vmcnt(0)" ::: "memory");
        __builtin_amdgcn_s_barrier();
        const char* ab = (const char*)&As[cur][0];
        const char* bb = (const char*)&Bs[cur][0];
        #pragma unroll
        for (int ks = 0; ks < 2; ++ks) {
            bf16x8 af[2], bfr[2];
            #pragma unroll
            for (int mi = 0; mi < 2; ++mi) af[mi]  = *(const bf16x8*)(ab + offA[mi][ks]);
            #pragma unroll
            for (int ni = 0; ni < 2; ++ni) bfr[ni] = *(const bf16x8*)(bb + offB[ni][ks]);
            #pragma unroll
            for (int mi = 0; mi < 2; ++mi)
                #pragma unroll
                for (int ni = 0; ni < 2; ++ni)
                    acc[mi][ni] = __builtin_amdgcn_mfma_f32_16x16x32_bf16(
                        af[mi], bfr[ni], acc[mi][ni], 0, 0, 0);
        }
        __builtin_amdgcn_s_barrier();
    }

    // C/D frag: col = l&15, row = (l>>4)*4 + j
    int n0 = bn * 64 + wc * 32 + l15;
    #pragma unroll
    for (int ni = 0; ni < 2; ++ni) {
        int n = n0 + ni * 16;
        float bv = bias ? bias[n] : 0.0f;
        #pragma unroll
        for (int mi = 0; mi < 2; ++mi) {
            int m = bm * 64 + wr * 32 + mi * 16 + lg * 4;
            #pragma unroll
            for (int j = 0; j < 4; ++j) {
                float v = silu_f(acc[mi][ni][j] + bv);
                if (COMPACT) {
                    int h = n >> 6, sc = n & 63;
                    if (sc < NTAP) {
                        unsigned u = tab[(size_t)(m + j) * (NH * NTAP) + sc * 8 + h];
                        float w = (float)__builtin_bit_cast(
                            _Float16, (unsigned short)(u & 0xFFFFu));
                        float t1 = v * w;
                        unsigned short c0 =
                            __builtin_bit_cast(unsigned short, (_Float16)(v - t1));
                        unsigned short c1 =
                            __builtin_bit_cast(unsigned short, (_Float16)t1);
                        uint2 qv;
                        qv.x = (unsigned)c0 | ((unsigned)c1 << 16);
                        qv.y = (u >> 16) << 11;          // byte offset i0*2048
                        qtab[(size_t)(m + j) * (NH * NTAP) + h * NTAP + sc] = qv;
                    }
                } else {
                    C[(size_t)(m + j) * 512 + n] = v;
                }
            }
        }
    }
}

// ---------------------------------------------------------------------------
// Gather conv (R10 structure, wave-local staging wait). One wave per (t,h);
// lane = dim d; batch = blockIdx.y. Stage the wave's 33 contiguous qtab
// entries into wave-private LDS (no block barrier — per-wave DS ordering,
// validated R7); per 11-tap chunk keep 11 gathers in flight, accumulate
// via v_dot2_f32_f16. XCD-aware block swizzle. Tiled bf16 hidden write.
// ---------------------------------------------------------------------------
__global__ __launch_bounds__(256, 4) void gather_conv(
    const unsigned* __restrict__ xpair, const uint2* __restrict__ qtab,
    __bf16* __restrict__ hb)
{
    __shared__ uint2 qs[4][NTAP + 3];

    int wid  = threadIdx.x >> 6;
    int lane = threadIdx.x & 63;
    int bid  = blockIdx.x;                       // 4096 = 8 XCDs * 512
    int nb   = ((bid & 7) << 9) | (bid >> 3);    // bijective XCD-chunked swizzle
    int wix  = nb * 4 + wid;                     // t*8 + h
    int h = wix & 7, t = wix >> 3;
    int b = blockIdx.y;

    int pos = b * LSEQ + t;
    const char* xpb = (const char*)xpair + (size_t)b * (LSEQ * 2048);
    int xoff = (h * HD + lane) * 4;
    const uint2* qp = qtab + (size_t)pos * (NH * NTAP) + h * NTAP;

    if (lane < NTAP) qs[wid][lane] = qp[lane];
    asm volatile("s_waitcnt lgkmcnt(0)" ::: "memory");
    __builtin_amdgcn_sched_barrier(0);

    float acc = 0.0f;
    #pragma unroll
    for (int c = 0; c < 3; ++c) {
        unsigned cx[11];
        unsigned gv[11];
        #pragma unroll
        for (int i = 0; i < 11; ++i) {
            uint2 q = qs[wid][c * 11 + i];
            cx[i] = q.x;
            unsigned off = __builtin_amdgcn_readfirstlane(q.y);
            gv[i] = *(const unsigned*)(xpb + off + xoff);
        }
        #pragma unroll
        for (int i = 0; i < 11; ++i) acc = fdot2f(cx[i], gv[i], acc);
    }

    // tiled+permuted+swizzled bf16 write; k-index = h*64 + lane, kt = h
    int tile = (pos >> 6) * 8 + h;
    int rowL = pos & 63;
    int d = lane, blk = d >> 5, kk = d & 31;
    int colp = blk * 32 + (kk & 3) + (((kk >> 4) & 1) << 2) + (((kk & 15) >> 2) << 3);
    int byteS = (colp * 2) ^ ((rowL & 7) << 4);
    hb[(size_t)tile * 4096 + rowL * 64 + (byteS >> 1)] = (__bf16)acc;
}

// ---------------------------------------------------------------------------
extern "C" void kernel_launch(void* const* d_in, const int* in_sizes, int n_in,
                              void* d_out, int out_size, void* d_ws, size_t ws_size,
                              hipStream_t stream)
{
    const float* x        = (const float*)d_in[0];
    const float* wave_w   = (const float*)d_in[1];
    const float* wave_b   = (const float*)d_in[2];
    const float* kernel_w = (const float*)d_in[3];
    const float* kernel_b = (const float*)d_in[4];
    const float* out_w    = (const float*)d_in[5];
    float* out = (float*)d_out;

    char* ws = (char*)d_ws;
    unsigned* tab   = (unsigned*)ws;  ws += (size_t)NPOS * NH * NTAP * 4;   // 4.33 MB
    uint2*    qtab  = (uint2*)ws;     ws += (size_t)NPOS * NH * NTAP * 8;   // 8.65 MB
    unsigned* xpair = (unsigned*)ws;  ws += (size_t)NPOS * CHN * 4;         // 8 MB
    __bf16*   xb    = (__bf16*)ws;    ws += (size_t)NPOS * CHN * 2;         // 4 MB
    __bf16*   kwb   = (__bf16*)ws;    ws += (size_t)CHN * CHN * 2;          // 0.5 MB
    __bf16*   owb   = (__bf16*)ws;    ws += (size_t)CHN * CHN * 2;          // 0.5 MB
    __bf16*   hidb  = xb;  // xb dead after GEMM1

    fused_prep<<<256 + NPOS / 4, 256, 0, stream>>>(
        x, wave_w, wave_b, kernel_w, kwb, out_w, owb, tab, xb, xpair);

    dim3 gg(NPOS / 64, CHN / 64);
    gemm_mfma64<true><<<gg, 256, 0, stream>>>(xb, kwb, kernel_b, nullptr, qtab, tab);

    gather_conv<<<dim3(LSEQ * NH / 4, 2), 256, 0, stream>>>(xpair, qtab, hidb);

    gemm_mfma64<false><<<gg, 256, 0, stream>>>(hidb, owb, nullptr, out, nullptr, nullptr);
}

// Round 13
// 51.951 us; speedup vs baseline: 1.0460x; 1.0458x over previous
//
#include <hip/hip_runtime.h>
#include <cstdint>
#include <cstddef>

#define LSEQ   2048
#define CHN    512
#define NH     8
#define HD     64
#define NTAP   33
#define NPOS   4096
#define MAXREC 256.0f

typedef __bf16   bf16x8 __attribute__((ext_vector_type(8)));
typedef __bf16   bf16x4 __attribute__((ext_vector_type(4)));
typedef float    f32x4  __attribute__((ext_vector_type(4)));
typedef _Float16 f16x2  __attribute__((ext_vector_type(2)));

__device__ __forceinline__ float silu_f(float v) {
    return v / (1.0f + expf(-v));
}

__device__ __forceinline__ void gload_lds16(const void* g, void* l) {
    __builtin_amdgcn_global_load_lds((const __attribute__((address_space(1))) void*)g,
                                     (__attribute__((address_space(3))) void*)l, 16, 0, 0);
}

__device__ __forceinline__ float fdot2f(unsigned a, unsigned b, float c) {
#if __has_builtin(__builtin_amdgcn_fdot2)
    return __builtin_amdgcn_fdot2(__builtin_bit_cast(f16x2, a),
                                  __builtin_bit_cast(f16x2, b), c, false);
#else
    f16x2 av = __builtin_bit_cast(f16x2, a);
    f16x2 bv = __builtin_bit_cast(f16x2, b);
    return c + (float)av[0] * (float)bv[0] + (float)av[1] * (float)bv[1];
#endif
}

// ---------------------------------------------------------------------------
// A-operand layout (xb/hidb): tiled bf16 (64 rows x 64 k per tile), k
// permuted per 32-block: col' = 32*(k/32) + (k%4) + 4*((k/16)&1) + 8*((k%16)/4)
// XOR bank swizzle on byte addr within row: byte ^= (row&7)<<4.
// One MFMA 16x16x32 A-fragment == one contiguous 16B ds_read_b128.
//
// B-operand layout (kwb/owb): FRAGMENT-MAJOR. Per tile (nt,kt) of 64n x 64k:
//   chunk c = (ks*4 + f)*64 + lane, lane = lg*16 + l15:
//     row  = nt*64 + f*16 + l15
//     elems k = kt*64 + ks*32 + lg*4 + {0..3} and + 16 + {0..3}
//   so each MFMA B-fragment (one wave, fixed ks,f) is a CONTIGUOUS 1 KB
//   block read as base + lane*16 — perfectly coalesced global->VGPR.
// ---------------------------------------------------------------------------

// ---------------------------------------------------------------------------
// Fused prep kernel. Grid 1280 blocks x 256 threads (R10 structure):
//   blocks [0,256):   convert kernel_w / out_w -> fragment-major bf16
//   blocks [256,1280): 4 positions/block: stage wave_w in LDS, x row ->
//       tiled bf16 xb, x pair rows -> xpair f16x2, matvec -> tap table.
// ---------------------------------------------------------------------------
__global__ __launch_bounds__(256) void fused_prep(
    const float* __restrict__ x, const float* __restrict__ ww,
    const float* __restrict__ wb,
    const float* __restrict__ kernel_w, __bf16* __restrict__ kwb,
    const float* __restrict__ out_w,    __bf16* __restrict__ owb,
    unsigned* __restrict__ tab, __bf16* __restrict__ xb,
    unsigned* __restrict__ xpair)
{
    __shared__ float wwS[16 * 512];
    __shared__ float fphS[4][16];

    int tid = threadIdx.x;
    if (blockIdx.x < 256) {
        // ---- weight conversion -> fragment-major B layout ----
        const float* src = (blockIdx.x < 128) ? kernel_w : out_w;
        __bf16*      dst = (blockIdx.x < 128) ? kwb : owb;
        int C = ((blockIdx.x & 127) * 256 + tid);   // [0, 32768)
        int tile = C >> 9;                          // 64 tiles of 512 chunks
        int c    = C & 511;
        int ks  = c >> 8;
        int f   = (c >> 6) & 3;
        int ln  = c & 63;
        int l15 = ln & 15, lg = ln >> 4;
        int row = (tile >> 3) * 64 + f * 16 + l15;
        int kb  = (tile & 7) * 64 + ks * 32 + lg * 4;
        const float* s = src + (size_t)row * 512 + kb;
        float4 v0 = *(const float4*)s;
        float4 v1 = *(const float4*)(s + 16);
        bf16x8 r;
        r[0] = (__bf16)v0.x; r[1] = (__bf16)v0.y; r[2] = (__bf16)v0.z; r[3] = (__bf16)v0.w;
        r[4] = (__bf16)v1.x; r[5] = (__bf16)v1.y; r[6] = (__bf16)v1.z; r[7] = (__bf16)v1.w;
        *(bf16x8*)(dst + (size_t)C * 8) = r;
        return;
    }

    // ---- wave path (R10 exact) ----
    #pragma unroll
    for (int j = 0; j < 8; ++j) {
        int idx = tid * 4 + j * 1024;
        *(float4*)&wwS[idx] = *(const float4*)&ww[idx];
    }

    int wid  = tid >> 6;
    int lane = tid & 63;
    int pos  = (blockIdx.x - 256) * 4 + wid;
    int t    = pos & (LSEQ - 1);

    const float* xrow = x + (size_t)pos * CHN;
    float4 xa = *(const float4*)(xrow + lane * 8);
    float4 xv = *(const float4*)(xrow + lane * 8 + 4);
    int nxt = (t == LSEQ - 1) ? pos : pos + 1;
    const float* nrow = x + (size_t)nxt * CHN;
    float4 na = *(const float4*)(nrow + lane * 8);
    float4 nv = *(const float4*)(nrow + lane * 8 + 4);
    float xs[8];
    #pragma unroll
    for (int j = 0; j < 8; ++j) xs[j] = xrow[lane + 64 * j];

    // tiled-bf16 store of this x row (A layout)
    {
        int kloc = (lane * 8) & 63;
        int kt   = lane >> 3;
        int rowL = pos & 63;
        int blk  = kloc >> 5;
        int kkA  = kloc & 31;
        int kkV  = kkA + 4;
        int colA = blk * 32 + 8 * ((kkA & 15) >> 2) + 4 * ((kkA >> 4) & 1);
        int colV = blk * 32 + 8 * ((kkV & 15) >> 2) + 4 * ((kkV >> 4) & 1);
        int sw   = (rowL & 7) << 4;
        char* base = (char*)xb + (((size_t)(pos >> 6) * 8 + kt) * 8192) + rowL * 128;
        bf16x4 va = { (__bf16)xa.x, (__bf16)xa.y, (__bf16)xa.z, (__bf16)xa.w };
        bf16x4 vv = { (__bf16)xv.x, (__bf16)xv.y, (__bf16)xv.z, (__bf16)xv.w };
        *(bf16x4*)(base + ((colA * 2) ^ sw)) = va;
        *(bf16x4*)(base + ((colV * 2) ^ sw)) = vv;
    }

    // xpair store: (f16 x[pos][d], f16 x[pos+1][d]) packed u32
    {
        float va8[8] = {xa.x, xa.y, xa.z, xa.w, xv.x, xv.y, xv.z, xv.w};
        float nb8[8] = {na.x, na.y, na.z, na.w, nv.x, nv.y, nv.z, nv.w};
        unsigned u[8];
        #pragma unroll
        for (int j = 0; j < 8; ++j) {
            unsigned short lo = __builtin_bit_cast(unsigned short, (_Float16)va8[j]);
            unsigned short hi = __builtin_bit_cast(unsigned short, (_Float16)nb8[j]);
            u[j] = (unsigned)lo | ((unsigned)hi << 16);
        }
        unsigned* dp = xpair + (size_t)pos * 512 + lane * 8;
        *(uint4*)dp       = make_uint4(u[0], u[1], u[2], u[3]);
        *(uint4*)(dp + 4) = make_uint4(u[4], u[5], u[6], u[7]);
    }

    __syncthreads();   // wwS ready

    #pragma unroll
    for (int o = 0; o < 16; ++o) {
        const float* wr = &wwS[o * 512 + lane];
        float p = 0.0f;
        #pragma unroll
        for (int j = 0; j < 8; ++j) p = fmaf(xs[j], wr[64 * j], p);
        #pragma unroll
        for (int off = 32; off > 0; off >>= 1) p += __shfl_xor(p, off);
        if (lane == 0) {
            float v = p + wb[o];
            float s = silu_f(v);
            fphS[wid][o] = (o < 8) ? (1.0f + 15.0f / (1.0f + expf(-s)))
                                   : (tanhf(s) * 16.0f);
        }
    }
    __syncthreads();

    // tap table: tab[pos*264 + s*8 + h] = (i0<<16) | f16bits(w)
    float tf = (float)t;
    float lo = fmaxf(tf - MAXREC, 0.0f);
    float hi = fminf(tf + MAXREC, (float)(LSEQ - 1));
    for (int it = lane; it < NH * NTAP; it += 64) {
        int h = it & 7, s = it >> 3;
        float f  = fphS[wid][h];
        float ph = fphS[wid][8 + h];
        float p = (tf + ph) + (float)(s - 16) * f;
        p = fminf(fmaxf(p, lo), hi);
        float p0 = floorf(p);
        float w  = p - p0;
        int i0 = (int)p0;
        if (i0 >= LSEQ - 1) { i0 = LSEQ - 2; w = 1.0f; }
        _Float16 hw = (_Float16)w;
        unsigned u = ((unsigned)i0 << 16) |
                     (unsigned)__builtin_bit_cast(unsigned short, hw);
        tab[(size_t)pos * (NH * NTAP) + it] = u;
    }
}

// ---------------------------------------------------------------------------
// bf16 MFMA GEMM, BM=BN=64, BK=64, 4 waves (2x2).
// A: global_load_lds double-buffered (16 KB LDS). B: fragment-major layout,
// streamed DIRECTLY global->VGPR — each fragment load is base + lane*16,
// one fully-coalesced 1 KB dwordx4 per wave (fixes R7's 64B-scatter).
// Double-buffered registers; kt loop fully unrolled (static breg indexing).
// Counted vmcnt(6) = 2 A-gloads + 4 B-loads in flight across the barrier.
// COMPACT: for taps sc=(n&63)<33, combine k=silu(acc+bias) with tab's (i0,w)
//          into qtab[pos][h][s] = { pack_f16(k*(1-w), k*w), i0*2048 }.
// else:    write full f32 silu'd [M,512].
// ---------------------------------------------------------------------------
template<bool COMPACT>
__global__ __launch_bounds__(256) void gemm_mfma64(
    const __bf16* __restrict__ At, const __bf16* __restrict__ Bt,
    const float* __restrict__ bias, float* __restrict__ C,
    uint2* __restrict__ qtab, const unsigned* __restrict__ tab)
{
    __shared__ __bf16 As[2][64 * 64];

    int bm = blockIdx.x, bn = blockIdx.y;
    int tid  = threadIdx.x;
    int lane = tid & 63;
    int wid  = tid >> 6;
    int wr = wid >> 1, wc = wid & 1;
    int lg = lane >> 4, l15 = lane & 15;

    const __bf16* Abase = At + (size_t)bm * 8 * 4096;
    const char*   Bbase = (const char*)(Bt + (size_t)bn * 8 * 4096);

    int offA[2][2];
    #pragma unroll
    for (int mi = 0; mi < 2; ++mi) {
        int row = wr * 32 + mi * 16 + l15;
        #pragma unroll
        for (int ks = 0; ks < 2; ++ks)
            offA[mi][ks] = row * 128 + (((ks << 6) | (lg << 4)) ^ ((row & 7) << 4));
    }
    // fragment-major B: frag f = wc*2 + ni; chunk = (ks*4 + f)*1024 + lane*16
    int offBf[2][2];
    #pragma unroll
    for (int ni = 0; ni < 2; ++ni)
        #pragma unroll
        for (int ks = 0; ks < 2; ++ks)
            offBf[ni][ks] = ((ks * 4 + wc * 2 + ni) << 10) + lane * 16;

    f32x4 acc[2][2] = {};
    bf16x8 breg[2][2][2];   // [buf][ni][ks] — static (kt loop fully unrolled)

    auto stageA = [&](int b, int kt) {
        const __bf16* ga = Abase + (size_t)kt * 4096 + tid * 8;
        __bf16* la = &As[b][tid * 8];
        #pragma unroll
        for (int c = 0; c < 2; ++c) gload_lds16(ga + c * 2048, la + c * 2048);
    };

    stageA(0, 0);
    #pragma unroll
    for (int ni = 0; ni < 2; ++ni)
        #pragma unroll
        for (int ks = 0; ks < 2; ++ks)
            breg[0][ni][ks] = *(const bf16x8*)(Bbase + offBf[ni][ks]);

    #pragma unroll
    for (int kt = 0; kt < 8; ++kt) {
        int cur = kt & 1;
        if (kt < 7) {
            stageA(cur ^ 1, kt + 1);
            #pragma unroll
            for (int ni = 0; ni < 2; ++ni)
                #pragma unroll
                for (int ks = 0; ks < 2; ++ks)
                    breg[cur ^ 1][ni][ks] =
                        *(const bf16x8*)(Bbase + (size_t)(kt + 1) * 8192 + offBf[ni][ks]);
        }
        __builtin_amdgcn_sched_barrier(0);
        if (kt < 7) asm volatile("s_waitcnt vmcnt(6)" ::: "memory");
        else        asm volatile("s_waitcnt vmcnt(0)" ::: "memory");
        __builtin_amdgcn_s_barrier();
        const char* ab = (const char*)&As[cur][0];
        #pragma unroll
        for (int ks = 0; ks < 2; ++ks) {
            bf16x8 af[2];
            #pragma unroll
            for (int mi = 0; mi < 2; ++mi) af[mi] = *(const bf16x8*)(ab + offA[mi][ks]);
            #pragma unroll
            for (int mi = 0; mi < 2; ++mi)
                #pragma unroll
                for (int ni = 0; ni < 2; ++ni)
                    acc[mi][ni] = __builtin_amdgcn_mfma_f32_16x16x32_bf16(
                        af[mi], breg[cur][ni][ks], acc[mi][ni], 0, 0, 0);
        }
        __builtin_amdgcn_s_barrier();
    }

    // C/D frag: col = l&15, row = (l>>4)*4 + j
    int n0 = bn * 64 + wc * 32 + l15;
    #pragma unroll
    for (int ni = 0; ni < 2; ++ni) {
        int n = n0 + ni * 16;
        float bv = bias ? bias[n] : 0.0f;
        #pragma unroll
        for (int mi = 0; mi < 2; ++mi) {
            int m = bm * 64 + wr * 32 + mi * 16 + lg * 4;
            #pragma unroll
            for (int j = 0; j < 4; ++j) {
                float v = silu_f(acc[mi][ni][j] + bv);
                if (COMPACT) {
                    int h = n >> 6, sc = n & 63;
                    if (sc < NTAP) {
                        unsigned u = tab[(size_t)(m + j) * (NH * NTAP) + sc * 8 + h];
                        float w = (float)__builtin_bit_cast(
                            _Float16, (unsigned short)(u & 0xFFFFu));
                        float t1 = v * w;
                        unsigned short c0 =
                            __builtin_bit_cast(unsigned short, (_Float16)(v - t1));
                        unsigned short c1 =
                            __builtin_bit_cast(unsigned short, (_Float16)t1);
                        uint2 qv;
                        qv.x = (unsigned)c0 | ((unsigned)c1 << 16);
                        qv.y = (u >> 16) << 11;          // byte offset i0*2048
                        qtab[(size_t)(m + j) * (NH * NTAP) + h * NTAP + sc] = qv;
                    }
                } else {
                    C[(size_t)(m + j) * 512 + n] = v;
                }
            }
        }
    }
}

// ---------------------------------------------------------------------------
// Gather conv (R10 exact). One wave per (t,h); lane = dim d; batch =
// blockIdx.y. Stage the wave's 33 contiguous qtab entries into LDS; per
// 11-tap chunk keep 11 gathers in flight, accumulate via v_dot2_f32_f16.
// XCD-aware block swizzle. Writes hidden as bf16 in the tiled A layout.
// ---------------------------------------------------------------------------
__global__ __launch_bounds__(256, 4) void gather_conv(
    const unsigned* __restrict__ xpair, const uint2* __restrict__ qtab,
    __bf16* __restrict__ hb)
{
    __shared__ uint2 qs[4][NTAP + 3];

    int wid  = threadIdx.x >> 6;
    int lane = threadIdx.x & 63;
    int bid  = blockIdx.x;                       // 4096 = 8 XCDs * 512
    int nb   = ((bid & 7) << 9) | (bid >> 3);    // bijective XCD-chunked swizzle
    int wix  = nb * 4 + wid;                     // t*8 + h
    int h = wix & 7, t = wix >> 3;
    int b = blockIdx.y;

    int pos = b * LSEQ + t;
    const char* xpb = (const char*)xpair + (size_t)b * (LSEQ * 2048);
    int xoff = (h * HD + lane) * 4;
    const uint2* qp = qtab + (size_t)pos * (NH * NTAP) + h * NTAP;

    if (lane < NTAP) qs[wid][lane] = qp[lane];
    __syncthreads();

    float acc = 0.0f;
    #pragma unroll
    for (int c = 0; c < 3; ++c) {
        unsigned cx[11];
        unsigned gv[11];
        #pragma unroll
        for (int i = 0; i < 11; ++i) {
            uint2 q = qs[wid][c * 11 + i];
            cx[i] = q.x;
            unsigned off = __builtin_amdgcn_readfirstlane(q.y);
            gv[i] = *(const unsigned*)(xpb + off + xoff);
        }
        #pragma unroll
        for (int i = 0; i < 11; ++i) acc = fdot2f(cx[i], gv[i], acc);
    }

    // tiled+permuted+swizzled bf16 write; k-index = h*64 + lane, kt = h
    int tile = (pos >> 6) * 8 + h;
    int rowL = pos & 63;
    int d = lane, blk = d >> 5, kk = d & 31;
    int colp = blk * 32 + (kk & 3) + (((kk >> 4) & 1) << 2) + (((kk & 15) >> 2) << 3);
    int byteS = (colp * 2) ^ ((rowL & 7) << 4);
    hb[(size_t)tile * 4096 + rowL * 64 + (byteS >> 1)] = (__bf16)acc;
}

// ---------------------------------------------------------------------------
extern "C" void kernel_launch(void* const* d_in, const int* in_sizes, int n_in,
                              void* d_out, int out_size, void* d_ws, size_t ws_size,
                              hipStream_t stream)
{
    const float* x        = (const float*)d_in[0];
    const float* wave_w   = (const float*)d_in[1];
    const float* wave_b   = (const float*)d_in[2];
    const float* kernel_w = (const float*)d_in[3];
    const float* kernel_b = (const float*)d_in[4];
    const float* out_w    = (const float*)d_in[5];
    float* out = (float*)d_out;

    char* ws = (char*)d_ws;
    unsigned* tab   = (unsigned*)ws;  ws += (size_t)NPOS * NH * NTAP * 4;   // 4.33 MB
    uint2*    qtab  = (uint2*)ws;     ws += (size_t)NPOS * NH * NTAP * 8;   // 8.65 MB
    unsigned* xpair = (unsigned*)ws;  ws += (size_t)NPOS * CHN * 4;         // 8 MB
    __bf16*   xb    = (__bf16*)ws;    ws += (size_t)NPOS * CHN * 2;         // 4 MB
    __bf16*   kwb   = (__bf16*)ws;    ws += (size_t)CHN * CHN * 2;          // 0.5 MB
    __bf16*   owb   = (__bf16*)ws;    ws += (size_t)CHN * CHN * 2;          // 0.5 MB
    __bf16*   hidb  = xb;  // xb dead after GEMM1

    fused_prep<<<256 + NPOS / 4, 256, 0, stream>>>(
        x, wave_w, wave_b, kernel_w, kwb, out_w, owb, tab, xb, xpair);

    dim3 gg(NPOS / 64, CHN / 64);
    gemm_mfma64<true><<<gg, 256, 0, stream>>>(xb, kwb, kernel_b, nullptr, qtab, tab);

    gather_conv<<<dim3(LSEQ * NH / 4, 2), 256, 0, stream>>>(xpair, qtab, hidb);

    gemm_mfma64<false><<<gg, 256, 0, stream>>>(hidb, owb, nullptr, out, nullptr, nullptr);
}